// Round 5
// baseline (4194.540 us; speedup 1.0000x reference)
//
#include <hip/hip_runtime.h>
#include <hip/hip_bf16.h>
#include <cstdint>
#include <cstddef>

#define D_MODEL 2048
#define NH 32
#define NKV 8
#define HD 64
#define BB 2
#define LL 2048
#define EPS 1e-6f

typedef __hip_bfloat16 bf16;

// ---- dtype-flex loads ------------------------------------------------------
__device__ inline float4 ld_bf4(const bf16* p) {
  const ushort4 u = *(const ushort4*)p;
  float4 r;
  r.x = __uint_as_float(((unsigned)u.x) << 16);
  r.y = __uint_as_float(((unsigned)u.y) << 16);
  r.z = __uint_as_float(((unsigned)u.z) << 16);
  r.w = __uint_as_float(((unsigned)u.w) << 16);
  return r;
}
__device__ inline float4 ld4_rt(const void* p, size_t i, bool f32) {
  if (f32) return *(const float4*)((const float*)p + i);
  return ld_bf4((const bf16*)p + i);
}
__device__ inline float ld1_rt(const void* p, size_t i, bool f32) {
  if (f32) return ((const float*)p)[i];
  unsigned short u = ((const unsigned short*)p)[i];
  return __uint_as_float(((unsigned)u) << 16);
}
__device__ inline unsigned short f2bf(float f) {
  bf16 h = __float2bfloat16(f);  // RNE
  return *reinterpret_cast<unsigned short*>(&h);
}
__device__ inline float bf2f(bf16 b) {
  unsigned short u = *reinterpret_cast<unsigned short*>(&b);
  return __uint_as_float(((unsigned)u) << 16);
}
__device__ inline void store4(float* p, float4 v) { *(float4*)p = v; }
__device__ inline void store4(bf16* p, float4 v) {
  ushort4 u;
  u.x = f2bf(v.x); u.y = f2bf(v.y); u.z = f2bf(v.z); u.w = f2bf(v.w);
  *(ushort4*)p = u;
}

// ---- per-input dtype detector ---------------------------------------------
// Word bits[14:7]==0xFF => bf16 NaN/Inf (impossible in finite bf16 data) or
// an f32 lo-mantissa word (~0.4% random chance). Any hit => input is f32.
__global__ __launch_bounds__(256) void detect_all(
    const unsigned short* p0, const unsigned short* p1, const unsigned short* p2,
    const unsigned short* p3, const unsigned short* p4, const unsigned short* p5,
    const unsigned short* p6, int* __restrict__ flags) {
  const unsigned short* ptrs[7] = {p0, p1, p2, p3, p4, p5, p6};
  const int ns[7] = {262144, 65536, 65536, 262144, 262144, 262144, 262144};
  const int b = blockIdx.x;
  const unsigned short* p = ptrs[b];
  const int n = ns[b];
  __shared__ int found;
  if (threadIdx.x == 0) found = 0;
  __syncthreads();
  int loc = 0;
  for (int i = threadIdx.x; i < n; i += 256)
    if (((p[i] >> 7) & 0xFF) == 0xFF) loc = 1;
  if (loc) atomicOr(&found, 1);
  __syncthreads();
  if (threadIdx.x == 0) flags[b] = found;
}

// ---------------------------------------------------------------------------
// GEMM: C[M,N] = A[M,K] @ W[K,N]. A dtype: flags[ia] (ia<0 => bf16 fixed).
// W dtype: flags[iw]. C: f32 or bf16. 64x64 tile, K16 LDS tiles, 4x4 micro.
// ---------------------------------------------------------------------------
template <typename CT>
__global__ __launch_bounds__(256) void gemm_dyn(const void* __restrict__ A,
                                                const void* __restrict__ W,
                                                CT* __restrict__ C,
                                                int M, int N, int K,
                                                const int* __restrict__ flags,
                                                int ia, int iw) {
  const bool af32 = (ia >= 0) && (flags[ia] != 0);
  const bool wf32 = (flags[iw] != 0);
  __shared__ float As[16][64];  // [k][m]
  __shared__ float Bs[16][64];  // [k][n]
  const int t = threadIdx.x;
  const int tx = t & 15, ty = t >> 4;
  const int m0 = blockIdx.y * 64, n0 = blockIdx.x * 64;
  float acc[4][4] = {};
  for (int k0 = 0; k0 < K; k0 += 16) {
    {
      int r = t >> 2, kc = (t & 3) << 2;
      float4 a4 = ld4_rt(A, (size_t)(m0 + r) * K + (k0 + kc), af32);
      As[kc + 0][r] = a4.x;
      As[kc + 1][r] = a4.y;
      As[kc + 2][r] = a4.z;
      As[kc + 3][r] = a4.w;
      int kr = t >> 4, nc = (t & 15) << 2;
      *(float4*)&Bs[kr][nc] = ld4_rt(W, (size_t)(k0 + kr) * N + (n0 + nc), wf32);
    }
    __syncthreads();
#pragma unroll
    for (int kk = 0; kk < 16; ++kk) {
      float4 a = *(const float4*)&As[kk][ty << 2];
      float4 b = *(const float4*)&Bs[kk][tx << 2];
      float av[4] = {a.x, a.y, a.z, a.w};
      float bv[4] = {b.x, b.y, b.z, b.w};
#pragma unroll
      for (int i = 0; i < 4; ++i)
#pragma unroll
        for (int j = 0; j < 4; ++j) acc[i][j] = fmaf(av[i], bv[j], acc[i][j]);
    }
    __syncthreads();
  }
#pragma unroll
  for (int i = 0; i < 4; ++i) {
    float4 o = make_float4(acc[i][0], acc[i][1], acc[i][2], acc[i][3]);
    store4(&C[(size_t)(m0 + (ty << 2) + i) * N + (n0 + (tx << 2))], o);
  }
}

// ---------------------------------------------------------------------------
// RoPE + RMSNorm in-place on bf16 q (B,L,NH,HD) and bf16 k (B,L,NKV,HD).
// One wave per (b,l,head). lane<32 holds x1[j], lane>=32 holds x2[j] (j=lane&31).
//   out1 = x1*c - x2*s  -> fmaf(val, c, -(other*s))
//   out2 = x2*c + x1*s  -> fmaf(val, c, +(other*s))   // R4 bug: had val/other swapped
// ---------------------------------------------------------------------------
__global__ __launch_bounds__(64) void rope_rms(bf16* __restrict__ q,
                                               bf16* __restrict__ k,
                                               const void* __restrict__ cosp,
                                               const void* __restrict__ sinp,
                                               const int* __restrict__ flags,
                                               int icos, int isin) {
  const bool cf = (flags[icos] != 0), sf = (flags[isin] != 0);
  const int idx = blockIdx.x;
  const int hh = idx % (NH + NKV);
  const int bl = idx / (NH + NKV);
  const int l = bl % LL;
  const int lane = threadIdx.x;
  const int j = lane & 31;
  float c = ld1_rt(cosp, l * 32 + j, cf);
  float s = ld1_rt(sinp, l * 32 + j, sf);
  bf16* base = (hh < NH) ? (q + ((size_t)bl * NH + hh) * HD)
                         : (k + ((size_t)bl * NKV + (hh - NH)) * HD);
  float val = bf2f(base[lane]);
  float other = __shfl_xor(val, 32);
  float r = (lane < 32) ? fmaf(val, c, -(other * s)) : fmaf(val, c, other * s);
  float ss = r * r;
#pragma unroll
  for (int off = 32; off; off >>= 1) ss += __shfl_xor(ss, off);
  base[lane] = __float2bfloat16(r * rsqrtf(ss * (1.0f / HD) + EPS));
}

// ---------------------------------------------------------------------------
// Causal GQA flash attention, all-bf16 buffers, f32 math.
// 256 threads handle 64 q-rows of one (b,h). O written IN-PLACE over q
// (each block reads exactly the region it writes; disjoint across blocks).
// ---------------------------------------------------------------------------
#define ASTRIDE 68
#define VSTRIDE 72
__global__ __launch_bounds__(256) void attn_fwd(bf16* __restrict__ qo,
                                                const bf16* __restrict__ k,
                                                const bf16* __restrict__ v) {
  __shared__ float Qs[64][ASTRIDE];
  __shared__ float Ks[64][ASTRIDE];
  __shared__ float Ss[64][ASTRIDE];
  __shared__ unsigned short Vs[64][VSTRIDE];
  __shared__ float mS[64], lS[64], aS[64];
  const int t = threadIdx.x;
  const int qt = blockIdx.x, h = blockIdx.y, b = blockIdx.z;
  const int kvh = h >> 2;
  const int q0 = qt * 64;
  const int r = t >> 2;
  const int c0 = (t & 3) << 4;
  float O[16];
#pragma unroll
  for (int i = 0; i < 16; ++i) O[i] = 0.f;
  if (t < 64) {
    mS[t] = -1e30f;
    lS[t] = 0.f;
  }
  {
    int row = t >> 4, d = (t & 15) << 2;
#pragma unroll
    for (int i = 0; i < 4; ++i) {
      float4 x = ld_bf4(&qo[(((size_t)b * LL + q0 + row + i * 16) * NH + h) * HD + d]);
      x.x *= 0.125f; x.y *= 0.125f; x.z *= 0.125f; x.w *= 0.125f;  // rsqrt(64)
      *(float4*)&Qs[row + i * 16][d] = x;
    }
  }
  __syncthreads();

  for (int j0 = 0; j0 <= q0; j0 += 64) {
    {
      int row = t >> 4, d = (t & 15) << 2;
#pragma unroll
      for (int i = 0; i < 4; ++i) {
        size_t g = (((size_t)b * LL + j0 + row + i * 16) * NKV + kvh) * HD + d;
        *(float4*)&Ks[row + i * 16][d] = ld_bf4(&k[g]);
        *(ushort4*)&Vs[row + i * 16][d] = *(const ushort4*)&v[g];
      }
    }
    __syncthreads();
    float sc[16];
#pragma unroll
    for (int cc = 0; cc < 16; ++cc) sc[cc] = 0.f;
#pragma unroll 4
    for (int d = 0; d < HD; d += 4) {
      float4 qv = *(const float4*)&Qs[r][d];
#pragma unroll
      for (int cc = 0; cc < 16; ++cc) {
        float4 kv = *(const float4*)&Ks[c0 + cc][d];
        sc[cc] = fmaf(qv.x, kv.x, sc[cc]);
        sc[cc] = fmaf(qv.y, kv.y, sc[cc]);
        sc[cc] = fmaf(qv.z, kv.z, sc[cc]);
        sc[cc] = fmaf(qv.w, kv.w, sc[cc]);
      }
    }
#pragma unroll
    for (int cc = 0; cc < 16; ++cc) {
      int ki = j0 + c0 + cc;
      Ss[r][c0 + cc] = (ki <= q0 + r) ? sc[cc] : -10000.0f;  // matches ref mask
    }
    __syncthreads();
    if (t < 64) {
      float mOld = mS[t];
      float mNew = mOld;
      for (int cc = 0; cc < 64; ++cc) mNew = fmaxf(mNew, Ss[t][cc]);
      float alpha = __expf(mOld - mNew);
      float lsum = 0.f;
      for (int cc = 0; cc < 64; ++cc) {
        float p = __expf(Ss[t][cc] - mNew);
        Ss[t][cc] = p;
        lsum += p;
      }
      lS[t] = lS[t] * alpha + lsum;
      mS[t] = mNew;
      aS[t] = alpha;
    }
    __syncthreads();
    float alpha = aS[r];
#pragma unroll
    for (int i = 0; i < 16; ++i) O[i] *= alpha;
    for (int kk = 0; kk < 64; ++kk) {
      float p = Ss[r][kk];
#pragma unroll
      for (int i = 0; i < 16; i += 4) {
        ushort4 vu = *(const ushort4*)&Vs[kk][c0 + i];
        O[i + 0] = fmaf(p, __uint_as_float(((unsigned)vu.x) << 16), O[i + 0]);
        O[i + 1] = fmaf(p, __uint_as_float(((unsigned)vu.y) << 16), O[i + 1]);
        O[i + 2] = fmaf(p, __uint_as_float(((unsigned)vu.z) << 16), O[i + 2]);
        O[i + 3] = fmaf(p, __uint_as_float(((unsigned)vu.w) << 16), O[i + 3]);
      }
    }
    __syncthreads();
  }
  const float invl = 1.0f / lS[r];
#pragma unroll
  for (int i = 0; i < 16; i += 4) {
    float4 ov = make_float4(O[i] * invl, O[i + 1] * invl, O[i + 2] * invl, O[i + 3] * invl);
    store4(&qo[(((size_t)b * LL + q0 + r) * NH + h) * HD + (c0 + i)], ov);
  }
}

// ---------------------------------------------------------------------------
extern "C" void kernel_launch(void* const* d_in, const int* in_sizes, int n_in,
                              void* d_out, int out_size, void* d_ws, size_t ws_size,
                              hipStream_t stream) {
  // setup_inputs() dict order: x, cos, sin, Wq, Wk, Wv, Wo (confirmed R1==R4)
  const void* x = d_in[0];
  const void* cosp = d_in[1];
  const void* sinp = d_in[2];
  const void* Wq = d_in[3];
  const void* Wk = d_in[4];
  const void* Wv = d_in[5];
  const void* Wo = d_in[6];
  float* out = (float*)d_out;

  const int M = BB * LL;  // 4096
  // ws: [flags 256 B][qo bf16 16.8 MB][kb bf16 4.2 MB][vb bf16 4.2 MB]
  char* w0 = (char*)d_ws;
  int* flags = (int*)w0;
  bf16* qo = (bf16*)(w0 + 256);
  bf16* kb = qo + (size_t)M * NH * HD;
  bf16* vb = kb + (size_t)M * NKV * HD;

  // 1) per-input dtype detection
  detect_all<<<7, 256, 0, stream>>>(
      (const unsigned short*)x, (const unsigned short*)cosp, (const unsigned short*)sinp,
      (const unsigned short*)Wq, (const unsigned short*)Wk, (const unsigned short*)Wv,
      (const unsigned short*)Wo, flags);
  // 2) QKV projections -> bf16
  gemm_dyn<bf16><<<dim3(D_MODEL / 64, M / 64), 256, 0, stream>>>(x, Wq, qo, M, D_MODEL, D_MODEL, flags, 0, 3);
  gemm_dyn<bf16><<<dim3((NKV * HD) / 64, M / 64), 256, 0, stream>>>(x, Wk, kb, M, NKV * HD, D_MODEL, flags, 0, 4);
  gemm_dyn<bf16><<<dim3((NKV * HD) / 64, M / 64), 256, 0, stream>>>(x, Wv, vb, M, NKV * HD, D_MODEL, flags, 0, 5);
  // 3) RoPE + RMSNorm in place on qo, kb
  rope_rms<<<M * (NH + NKV), 64, 0, stream>>>(qo, kb, cosp, sinp, flags, 1, 2);
  // 4) causal GQA attention, output in-place over qo
  attn_fwd<<<dim3(LL / 64, NH, BB), 256, 0, stream>>>(qo, kb, vb);
  // 5) output projection -> f32 d_out
  gemm_dyn<float><<<dim3(D_MODEL / 64, M / 64), 256, 0, stream>>>(qo, Wo, out, M, D_MODEL, D_MODEL, flags, -1, 6);
}

// Round 6
// 717.800 us; speedup vs baseline: 5.8436x; 5.8436x over previous
//
#include <hip/hip_runtime.h>
#include <hip/hip_bf16.h>
#include <cstdint>
#include <cstddef>

#define D_MODEL 2048
#define NH 32
#define NKV 8
#define HD 64
#define BB 2
#define LL 2048
#define EPS 1e-6f
#define MM (BB * LL)  // 4096

typedef __hip_bfloat16 bf16;
typedef short bf16x8 __attribute__((ext_vector_type(8)));
typedef float f32x4 __attribute__((ext_vector_type(4)));

// ---- dtype helpers ---------------------------------------------------------
__device__ inline float4 ld_bf4u(const unsigned short* p) {
  const ushort4 u = *(const ushort4*)p;
  float4 r;
  r.x = __uint_as_float(((unsigned)u.x) << 16);
  r.y = __uint_as_float(((unsigned)u.y) << 16);
  r.z = __uint_as_float(((unsigned)u.z) << 16);
  r.w = __uint_as_float(((unsigned)u.w) << 16);
  return r;
}
__device__ inline float4 ld4_rt(const void* p, size_t i, bool f32) {
  if (f32) return *(const float4*)((const float*)p + i);
  return ld_bf4u((const unsigned short*)p + i);
}
__device__ inline float ld1_rt(const void* p, size_t i, bool f32) {
  if (f32) return ((const float*)p)[i];
  unsigned short u = ((const unsigned short*)p)[i];
  return __uint_as_float(((unsigned)u) << 16);
}
__device__ inline unsigned short f2bf(float f) {
  bf16 h = __float2bfloat16(f);  // RNE
  return *reinterpret_cast<unsigned short*>(&h);
}
__device__ inline float bfu2f(unsigned short u) {
  return __uint_as_float(((unsigned)u) << 16);
}
__device__ inline void store1(float* p, float v) { *p = v; }
__device__ inline void store1(unsigned short* p, float v) { *p = f2bf(v); }

// ---- per-input dtype detector (kept from R5 — cheap insurance) -------------
__global__ __launch_bounds__(256) void detect_all(
    const unsigned short* p0, const unsigned short* p1, const unsigned short* p2,
    const unsigned short* p3, const unsigned short* p4, const unsigned short* p5,
    const unsigned short* p6, int* __restrict__ flags) {
  const unsigned short* ptrs[7] = {p0, p1, p2, p3, p4, p5, p6};
  const int ns[7] = {262144, 65536, 65536, 262144, 262144, 262144, 262144};
  const int b = blockIdx.x;
  const unsigned short* p = ptrs[b];
  const int n = ns[b];
  __shared__ int found;
  if (threadIdx.x == 0) found = 0;
  __syncthreads();
  int loc = 0;
  for (int i = threadIdx.x; i < n; i += 256)
    if (((p[i] >> 7) & 0xFF) == 0xFF) loc = 1;
  if (loc) atomicOr(&found, 1);
  __syncthreads();
  if (threadIdx.x == 0) flags[b] = found;
}

// ---- prep: elementwise convert to bf16 -------------------------------------
__global__ __launch_bounds__(256) void cvt_bf16(const void* __restrict__ src,
                                                unsigned short* __restrict__ dst,
                                                int n4, const int* __restrict__ flags, int idx) {
  const bool f32 = flags[idx] != 0;
  int i = blockIdx.x * 256 + threadIdx.x;
  if (i < n4) {
    float4 v = ld4_rt(src, (size_t)i * 4, f32);
    ushort4 o;
    o.x = f2bf(v.x); o.y = f2bf(v.y); o.z = f2bf(v.z); o.w = f2bf(v.w);
    *(ushort4*)&dst[(size_t)i * 4] = o;
  }
}

// ---- prep: transpose [K][N] -> [N][K] bf16 (64x64 LDS tiles) ---------------
__global__ __launch_bounds__(256) void transpose_any(const void* __restrict__ src,
                                                     unsigned short* __restrict__ dst,
                                                     int K, int N,
                                                     const int* __restrict__ flags, int idx) {
  const bool f32 = flags[idx] != 0;
  __shared__ unsigned short tile[64][65];
  const int t = threadIdx.x;
  const int n0 = blockIdx.x * 64, k0 = blockIdx.y * 64;
  const int cr = t >> 4, cc = (t & 15) * 4;
#pragma unroll
  for (int rr = 0; rr < 4; ++rr) {
    int row = rr * 16 + cr;  // k-local
    float4 v = ld4_rt(src, (size_t)(k0 + row) * N + n0 + cc, f32);
    tile[row][cc + 0] = f2bf(v.x);
    tile[row][cc + 1] = f2bf(v.y);
    tile[row][cc + 2] = f2bf(v.z);
    tile[row][cc + 3] = f2bf(v.w);
  }
  __syncthreads();
#pragma unroll
  for (int rr = 0; rr < 4; ++rr) {
    int nrow = rr * 16 + cr;  // n-local
    ushort4 o;
    o.x = tile[cc + 0][nrow];
    o.y = tile[cc + 1][nrow];
    o.z = tile[cc + 2][nrow];
    o.w = tile[cc + 3][nrow];
    *(ushort4*)&dst[(size_t)(n0 + nrow) * K + k0 + cc] = o;
  }
}

// ---------------------------------------------------------------------------
// MFMA GEMM: C[M,N] = A[M,K] (bf16) @ Bt[N,K]^T (bf16). 128x128 block tile,
// BK=32, 4 waves (2x2), each wave 64x64 = 4x4 tiles of 16x16x32 MFMA.
// ---------------------------------------------------------------------------
template <typename CT>
__global__ __launch_bounds__(256) void gemm_mfma(const unsigned short* __restrict__ A,
                                                 const unsigned short* __restrict__ Bt,
                                                 CT* __restrict__ C,
                                                 int M, int N, int K) {
  __shared__ unsigned short As[128][32];
  __shared__ unsigned short Bs[128][32];
  const int t = threadIdx.x;
  const int lane = t & 63, w = t >> 6;
  const int wm = (w >> 1) * 64, wn = (w & 1) * 64;
  const int g = lane >> 4, m16 = lane & 15;
  const int m0 = blockIdx.y * 128, n0 = blockIdx.x * 128;
  const int sr = t >> 1, ss = (t & 1) * 16;  // staging: row, 16-elem seg
  f32x4 acc[4][4] = {};
  for (int k0 = 0; k0 < K; k0 += 32) {
    uint4 a0 = *(const uint4*)&A[(size_t)(m0 + sr) * K + k0 + ss];
    uint4 a1 = *(const uint4*)&A[(size_t)(m0 + sr) * K + k0 + ss + 8];
    uint4 b0 = *(const uint4*)&Bt[(size_t)(n0 + sr) * K + k0 + ss];
    uint4 b1 = *(const uint4*)&Bt[(size_t)(n0 + sr) * K + k0 + ss + 8];
    __syncthreads();  // protect previous iteration's frag reads
    *(uint4*)&As[sr][ss] = a0;
    *(uint4*)&As[sr][ss + 8] = a1;
    *(uint4*)&Bs[sr][ss] = b0;
    *(uint4*)&Bs[sr][ss + 8] = b1;
    __syncthreads();
    bf16x8 af[4], bfr[4];
#pragma unroll
    for (int i = 0; i < 4; ++i) af[i] = *(const bf16x8*)&As[wm + i * 16 + m16][g * 8];
#pragma unroll
    for (int j = 0; j < 4; ++j) bfr[j] = *(const bf16x8*)&Bs[wn + j * 16 + m16][g * 8];
#pragma unroll
    for (int i = 0; i < 4; ++i)
#pragma unroll
      for (int j = 0; j < 4; ++j)
        acc[i][j] = __builtin_amdgcn_mfma_f32_16x16x32_bf16(af[i], bfr[j], acc[i][j], 0, 0, 0);
  }
#pragma unroll
  for (int i = 0; i < 4; ++i)
#pragma unroll
    for (int j = 0; j < 4; ++j)
#pragma unroll
      for (int r = 0; r < 4; ++r) {
        int row = m0 + wm + i * 16 + g * 4 + r;
        int col = n0 + wn + j * 16 + m16;
        store1(&C[(size_t)row * N + col], acc[i][j][r]);
      }
}

// ---------------------------------------------------------------------------
// RoPE + RMSNorm in place. q: [M][2048] bf16 (col = h*64+d). kv: [M][1024]
// bf16 (col = kvh*64+d for K half; V half untouched). 4 waves/block, one
// (b,l,head) per wave.
// ---------------------------------------------------------------------------
__global__ __launch_bounds__(256) void rope_rms(unsigned short* __restrict__ q,
                                                unsigned short* __restrict__ kv,
                                                const void* __restrict__ cosp,
                                                const void* __restrict__ sinp,
                                                const int* __restrict__ flags) {
  const bool cf = flags[1] != 0, sf = flags[2] != 0;
  const int wid = blockIdx.x * 4 + (threadIdx.x >> 6);
  const int lane = threadIdx.x & 63;
  const int hh = wid % (NH + NKV);
  const int bl = wid / (NH + NKV);
  const int l = bl & (LL - 1);
  unsigned short* base = (hh < NH) ? &q[(size_t)bl * 2048 + hh * 64]
                                   : &kv[(size_t)bl * 1024 + (hh - NH) * 64];
  const int j = lane & 31;
  float c = ld1_rt(cosp, l * 32 + j, cf);
  float s = ld1_rt(sinp, l * 32 + j, sf);
  float val = bfu2f(base[lane]);
  float other = __shfl_xor(val, 32);
  float r = (lane < 32) ? fmaf(val, c, -(other * s)) : fmaf(val, c, other * s);
  float ss = r * r;
#pragma unroll
  for (int off = 32; off; off >>= 1) ss += __shfl_xor(ss, off);
  base[lane] = f2bf(r * rsqrtf(ss * (1.0f / HD) + EPS));
}

// ---------------------------------------------------------------------------
// MFMA causal GQA flash attention.
// Block = 4 waves; wave w owns q-rows [q0+w*16, +16) of one (b,h).
// Per 64-key tile: K staged [j][d], V staged transposed [d][key];
// QK^T: 8 MFMA; online softmax in registers (16-lane shfl butterflies);
// P -> LDS (C-layout) -> A-layout frags; PV: 8 MFMA.
// ---------------------------------------------------------------------------
__global__ __launch_bounds__(256) void attn_mfma(const unsigned short* __restrict__ q,
                                                 const unsigned short* __restrict__ kv,
                                                 unsigned short* __restrict__ o) {
  __shared__ unsigned short Ks[64][72];      // [key][d]
  __shared__ unsigned short Vs[64][72];      // [d][key] (transposed)
  __shared__ unsigned short Ps[4][16][72];   // per-wave P round-trip
  const int t = threadIdx.x, lane = t & 63, w = t >> 6;
  const int g = lane >> 4, m16 = lane & 15;
  const int qt = blockIdx.x, h = blockIdx.y, b = blockIdx.z;
  const int kvh = h >> 2;
  const int q0 = qt * 64, qr0 = q0 + w * 16;

  // Q fragments (A-layout), scale folded into S later
  bf16x8 qf[2];
  {
    const unsigned short* qrow = &q[(size_t)(b * LL + qr0 + m16) * 2048 + h * 64 + g * 8];
    qf[0] = *(const bf16x8*)&qrow[0];
    qf[1] = *(const bf16x8*)&qrow[32];
  }
  f32x4 Oacc[4] = {};
  float mrow[4], lrow[4];
#pragma unroll
  for (int r = 0; r < 4; ++r) { mrow[r] = -1e30f; lrow[r] = 0.f; }

  const int kcol = kvh * 64, vcol = 512 + kvh * 64;

  for (int j0 = 0; j0 <= q0; j0 += 64) {
    __syncthreads();  // staging overwrite safety
    {
      // K: thread copies 32 B of row (t&63), seg (t>>6)
      int kr = t & 63, seg = (t >> 6) * 16;
      const unsigned short* src = &kv[(size_t)(b * LL + j0 + kr) * 1024 + kcol + seg];
      *(uint4*)&Ks[kr][seg] = *(const uint4*)&src[0];
      *(uint4*)&Ks[kr][seg + 8] = *(const uint4*)&src[8];
      // V transposed: thread reads 16 d of key (t&63), scatters to Vs[d][key]
      const unsigned short* vsrc = &kv[(size_t)(b * LL + j0 + kr) * 1024 + vcol + seg];
      ushort4 v0 = *(const ushort4*)&vsrc[0];
      ushort4 v1 = *(const ushort4*)&vsrc[4];
      ushort4 v2 = *(const ushort4*)&vsrc[8];
      ushort4 v3 = *(const ushort4*)&vsrc[12];
      unsigned short vv[16];
      *(ushort4*)&vv[0] = v0; *(ushort4*)&vv[4] = v1;
      *(ushort4*)&vv[8] = v2; *(ushort4*)&vv[12] = v3;
#pragma unroll
      for (int jj = 0; jj < 16; ++jj) Vs[seg + jj][kr] = vv[jj];
    }
    __syncthreads();

    // S = Q K^T  (S[jt] tile: rows qr0+g*4+r, cols j0+jt*16+m16)
    f32x4 S[4];
#pragma unroll
    for (int jt = 0; jt < 4; ++jt) {
      bf16x8 kf0 = *(const bf16x8*)&Ks[jt * 16 + m16][g * 8];
      bf16x8 kf1 = *(const bf16x8*)&Ks[jt * 16 + m16][32 + g * 8];
      f32x4 z = {0.f, 0.f, 0.f, 0.f};
      z = __builtin_amdgcn_mfma_f32_16x16x32_bf16(qf[0], kf0, z, 0, 0, 0);
      S[jt] = __builtin_amdgcn_mfma_f32_16x16x32_bf16(qf[1], kf1, z, 0, 0, 0);
    }
    // scale + causal mask
#pragma unroll
    for (int jt = 0; jt < 4; ++jt)
#pragma unroll
      for (int r = 0; r < 4; ++r) {
        int col = j0 + jt * 16 + m16;
        int row = qr0 + g * 4 + r;
        float s = S[jt][r] * 0.125f;
        S[jt][r] = (col <= row) ? s : -10000.0f;
      }
    // online softmax update (per row r; 16-lane butterfly over cols)
    float alpha[4], mnew[4];
#pragma unroll
    for (int r = 0; r < 4; ++r) {
      float mx = fmaxf(fmaxf(S[0][r], S[1][r]), fmaxf(S[2][r], S[3][r]));
#pragma unroll
      for (int off = 1; off < 16; off <<= 1) mx = fmaxf(mx, __shfl_xor(mx, off));
      mnew[r] = fmaxf(mrow[r], mx);
      alpha[r] = __expf(mrow[r] - mnew[r]);
      mrow[r] = mnew[r];
    }
    float rs[4] = {0.f, 0.f, 0.f, 0.f};
#pragma unroll
    for (int jt = 0; jt < 4; ++jt)
#pragma unroll
      for (int r = 0; r < 4; ++r) {
        float p = __expf(S[jt][r] - mnew[r]);
        S[jt][r] = p;
        rs[r] += p;
      }
#pragma unroll
    for (int r = 0; r < 4; ++r) {
#pragma unroll
      for (int off = 1; off < 16; off <<= 1) rs[r] += __shfl_xor(rs[r], off);
      lrow[r] = lrow[r] * alpha[r] + rs[r];
    }
    // P -> LDS (C-layout write), then read back as A-layout frags
#pragma unroll
    for (int jt = 0; jt < 4; ++jt)
#pragma unroll
      for (int r = 0; r < 4; ++r)
        Ps[w][g * 4 + r][jt * 16 + m16] = f2bf(S[jt][r]);
    __syncthreads();
    bf16x8 pf0 = *(const bf16x8*)&Ps[w][m16][g * 8];
    bf16x8 pf1 = *(const bf16x8*)&Ps[w][m16][32 + g * 8];
    // O = O*alpha + P V
#pragma unroll
    for (int dt = 0; dt < 4; ++dt) {
      bf16x8 vf0 = *(const bf16x8*)&Vs[dt * 16 + m16][g * 8];
      bf16x8 vf1 = *(const bf16x8*)&Vs[dt * 16 + m16][32 + g * 8];
#pragma unroll
      for (int r = 0; r < 4; ++r) Oacc[dt][r] *= alpha[r];
      Oacc[dt] = __builtin_amdgcn_mfma_f32_16x16x32_bf16(pf0, vf0, Oacc[dt], 0, 0, 0);
      Oacc[dt] = __builtin_amdgcn_mfma_f32_16x16x32_bf16(pf1, vf1, Oacc[dt], 0, 0, 0);
    }
  }
  // epilogue: divide by l, store bf16 (b,l,h,d)
#pragma unroll
  for (int dt = 0; dt < 4; ++dt)
#pragma unroll
    for (int r = 0; r < 4; ++r) {
      int row = qr0 + g * 4 + r;
      o[(size_t)(b * LL + row) * 2048 + h * 64 + dt * 16 + m16] = f2bf(Oacc[dt][r] / lrow[r]);
    }
}

// ---------------------------------------------------------------------------
extern "C" void kernel_launch(void* const* d_in, const int* in_sizes, int n_in,
                              void* d_out, int out_size, void* d_ws, size_t ws_size,
                              hipStream_t stream) {
  const void* x = d_in[0];
  const void* cosp = d_in[1];
  const void* sinp = d_in[2];
  const void* Wq = d_in[3];
  const void* Wk = d_in[4];
  const void* Wv = d_in[5];
  const void* Wo = d_in[6];
  float* out = (float*)d_out;

  // ws layout (bf16 elements), ~63 MB total:
  char* w0 = (char*)d_ws;
  int* flags = (int*)w0;
  unsigned short* xb = (unsigned short*)(w0 + 256);      // [4096][2048]; reused as ao
  unsigned short* qb = xb + (size_t)MM * 2048;           // [4096][2048]
  unsigned short* kvb = qb + (size_t)MM * 2048;          // [4096][1024] (k|v)
  unsigned short* WqT = kvb + (size_t)MM * 1024;         // [2048][2048]
  unsigned short* WkvT = WqT + (size_t)2048 * 2048;      // [1024][2048] (Wk^T ; Wv^T)
  unsigned short* WoT = WkvT + (size_t)1024 * 2048;      // [2048][2048]

  // 1) dtype detection
  detect_all<<<7, 256, 0, stream>>>(
      (const unsigned short*)x, (const unsigned short*)cosp, (const unsigned short*)sinp,
      (const unsigned short*)Wq, (const unsigned short*)Wk, (const unsigned short*)Wv,
      (const unsigned short*)Wo, flags);
  // 2) prep: x -> bf16; weights -> transposed bf16
  cvt_bf16<<<(MM * 2048 / 4 + 255) / 256, 256, 0, stream>>>(x, xb, MM * 2048 / 4, flags, 0);
  transpose_any<<<dim3(2048 / 64, 2048 / 64), 256, 0, stream>>>(Wq, WqT, 2048, 2048, flags, 3);
  transpose_any<<<dim3(512 / 64, 2048 / 64), 256, 0, stream>>>(Wk, WkvT, 2048, 512, flags, 4);
  transpose_any<<<dim3(512 / 64, 2048 / 64), 256, 0, stream>>>(Wv, WkvT + (size_t)512 * 2048, 2048, 512, flags, 5);
  transpose_any<<<dim3(2048 / 64, 2048 / 64), 256, 0, stream>>>(Wo, WoT, 2048, 2048, flags, 6);
  // 3) projections (MFMA)
  gemm_mfma<unsigned short><<<dim3(2048 / 128, MM / 128), 256, 0, stream>>>(xb, WqT, qb, MM, 2048, 2048);
  gemm_mfma<unsigned short><<<dim3(1024 / 128, MM / 128), 256, 0, stream>>>(xb, WkvT, kvb, MM, 1024, 2048);
  // 4) RoPE + RMSNorm in place
  rope_rms<<<MM * (NH + NKV) / 4, 256, 0, stream>>>(qb, kvb, cosp, sinp, flags);
  // 5) causal GQA attention (MFMA) -> ao (= xb)
  attn_mfma<<<dim3(LL / 64, NH, BB), 256, 0, stream>>>(qb, kvb, xb);
  // 6) output projection -> f32
  gemm_mfma<float><<<dim3(2048 / 128, MM / 128), 256, 0, stream>>>(xb, WoT, out, MM, 2048, 2048);
}

// Round 7
// 589.913 us; speedup vs baseline: 7.1104x; 1.2168x over previous
//
#include <hip/hip_runtime.h>
#include <hip/hip_bf16.h>
#include <cstdint>
#include <cstddef>

#define D_MODEL 2048
#define NH 32
#define NKV 8
#define HD 64
#define BB 2
#define LL 2048
#define EPS 1e-6f
#define MM (BB * LL)   // 4096
#define QS 3072        // fused qkv row stride
#define KO 2048        // k column offset in qkv
#define VO 2560        // v column offset in qkv

typedef __hip_bfloat16 bf16;
typedef short bf16x8 __attribute__((ext_vector_type(8)));
typedef float f32x4 __attribute__((ext_vector_type(4)));

// ---- dtype helpers ---------------------------------------------------------
__device__ inline float4 ld_bf4u(const unsigned short* p) {
  const ushort4 u = *(const ushort4*)p;
  float4 r;
  r.x = __uint_as_float(((unsigned)u.x) << 16);
  r.y = __uint_as_float(((unsigned)u.y) << 16);
  r.z = __uint_as_float(((unsigned)u.z) << 16);
  r.w = __uint_as_float(((unsigned)u.w) << 16);
  return r;
}
__device__ inline float4 ld4_rt(const void* p, size_t i, bool f32) {
  if (f32) return *(const float4*)((const float*)p + i);
  return ld_bf4u((const unsigned short*)p + i);
}
__device__ inline float ld1_rt(const void* p, size_t i, bool f32) {
  if (f32) return ((const float*)p)[i];
  unsigned short u = ((const unsigned short*)p)[i];
  return __uint_as_float(((unsigned)u) << 16);
}
__device__ inline unsigned short f2bf(float f) {
  bf16 h = __float2bfloat16(f);  // RNE
  return *reinterpret_cast<unsigned short*>(&h);
}
__device__ inline float bfu2f(unsigned short u) {
  return __uint_as_float(((unsigned)u) << 16);
}
__device__ inline void store1(float* p, float v) { *p = v; }
__device__ inline void store1(unsigned short* p, float v) { *p = f2bf(v); }

// async global->LDS, 16 B per lane; LDS dest must be wave-uniform base + lane*16
__device__ inline void glds16(const unsigned short* g, unsigned short* l) {
  __builtin_amdgcn_global_load_lds(
      (const __attribute__((address_space(1))) unsigned int*)g,
      (__attribute__((address_space(3))) unsigned int*)l, 16, 0, 0);
}

// ---- per-input dtype detector (cheap insurance) ----------------------------
__global__ __launch_bounds__(256) void detect_all(
    const unsigned short* p0, const unsigned short* p1, const unsigned short* p2,
    const unsigned short* p3, const unsigned short* p4, const unsigned short* p5,
    const unsigned short* p6, int* __restrict__ flags) {
  const unsigned short* ptrs[7] = {p0, p1, p2, p3, p4, p5, p6};
  const int ns[7] = {262144, 65536, 65536, 262144, 262144, 262144, 262144};
  const int b = blockIdx.x;
  const unsigned short* p = ptrs[b];
  const int n = ns[b];
  __shared__ int found;
  if (threadIdx.x == 0) found = 0;
  __syncthreads();
  int loc = 0;
  for (int i = threadIdx.x; i < n; i += 256)
    if (((p[i] >> 7) & 0xFF) == 0xFF) loc = 1;
  if (loc) atomicOr(&found, 1);
  __syncthreads();
  if (threadIdx.x == 0) flags[b] = found;
}

// ---- prep: elementwise convert to bf16 -------------------------------------
__global__ __launch_bounds__(256) void cvt_bf16(const void* __restrict__ src,
                                                unsigned short* __restrict__ dst,
                                                int n4, const int* __restrict__ flags, int idx) {
  const bool f32 = flags[idx] != 0;
  int i = blockIdx.x * 256 + threadIdx.x;
  if (i < n4) {
    float4 v = ld4_rt(src, (size_t)i * 4, f32);
    ushort4 o;
    o.x = f2bf(v.x); o.y = f2bf(v.y); o.z = f2bf(v.z); o.w = f2bf(v.w);
    *(ushort4*)&dst[(size_t)i * 4] = o;
  }
}

// ---- prep: transpose [K][N] -> [N][K] bf16 ---------------------------------
__global__ __launch_bounds__(256) void transpose_any(const void* __restrict__ src,
                                                     unsigned short* __restrict__ dst,
                                                     int K, int N,
                                                     const int* __restrict__ flags, int idx) {
  const bool f32 = flags[idx] != 0;
  __shared__ unsigned short tile[64][65];
  const int t = threadIdx.x;
  const int n0 = blockIdx.x * 64, k0 = blockIdx.y * 64;
  const int cr = t >> 4, cc = (t & 15) * 4;
#pragma unroll
  for (int rr = 0; rr < 4; ++rr) {
    int row = rr * 16 + cr;
    float4 v = ld4_rt(src, (size_t)(k0 + row) * N + n0 + cc, f32);
    tile[row][cc + 0] = f2bf(v.x);
    tile[row][cc + 1] = f2bf(v.y);
    tile[row][cc + 2] = f2bf(v.z);
    tile[row][cc + 3] = f2bf(v.w);
  }
  __syncthreads();
#pragma unroll
  for (int rr = 0; rr < 4; ++rr) {
    int nrow = rr * 16 + cr;
    ushort4 o;
    o.x = tile[cc + 0][nrow];
    o.y = tile[cc + 1][nrow];
    o.z = tile[cc + 2][nrow];
    o.w = tile[cc + 3][nrow];
    *(ushort4*)&dst[(size_t)(n0 + nrow) * K + k0 + cc] = o;
  }
}

// ---------------------------------------------------------------------------
// MFMA GEMM (m97 structure): C[M,N] = A[M,K]@Bt[N,K]^T, bf16 in, CT out.
// 128x128 tile, BK=32, global_load_lds width-16 staging, 2-barrier K-loop.
// ---------------------------------------------------------------------------
template <typename CT>
__global__ __launch_bounds__(256) void gemm_mfma(const unsigned short* __restrict__ A,
                                                 const unsigned short* __restrict__ Bt,
                                                 CT* __restrict__ C,
                                                 int M, int N, int K, int lda) {
  __shared__ __align__(16) unsigned short As[128 * 32];  // row-major [128][32]
  __shared__ __align__(16) unsigned short Bs[128 * 32];
  const int t = threadIdx.x;
  const int lane = t & 63, w = t >> 6;
  const int wm = (w >> 1) * 64, wn = (w & 1) * 64;
  const int g = lane >> 4, m16 = lane & 15;
  const int m0 = blockIdx.y * 128, n0 = blockIdx.x * 128;
  // staging: thread t covers row t/4, k-seg (t%4)*8 shorts (16 B); LDS dest = t*16 B
  const unsigned short* gA = &A[(size_t)(m0 + (t >> 2)) * lda + (t & 3) * 8];
  const unsigned short* gB = &Bt[(size_t)(n0 + (t >> 2)) * K + (t & 3) * 8];
  unsigned short* lA = &As[t * 8];
  unsigned short* lB = &Bs[t * 8];
  f32x4 acc[4][4] = {};
  for (int k0 = 0; k0 < K; k0 += 32) {
    __syncthreads();  // prev iteration's frag reads done
    glds16(gA + k0, lA);
    glds16(gA + (size_t)64 * lda + k0, lA + 2048);
    glds16(gB + k0, lB);
    glds16(gB + (size_t)64 * K + k0, lB + 2048);
    __syncthreads();  // drains vmcnt -> staged data visible
    bf16x8 af[4], bfr[4];
#pragma unroll
    for (int i = 0; i < 4; ++i) af[i] = *(const bf16x8*)&As[(wm + i * 16 + m16) * 32 + g * 8];
#pragma unroll
    for (int j = 0; j < 4; ++j) bfr[j] = *(const bf16x8*)&Bs[(wn + j * 16 + m16) * 32 + g * 8];
#pragma unroll
    for (int i = 0; i < 4; ++i)
#pragma unroll
      for (int j = 0; j < 4; ++j)
        acc[i][j] = __builtin_amdgcn_mfma_f32_16x16x32_bf16(af[i], bfr[j], acc[i][j], 0, 0, 0);
  }
#pragma unroll
  for (int i = 0; i < 4; ++i)
#pragma unroll
    for (int j = 0; j < 4; ++j)
#pragma unroll
      for (int r = 0; r < 4; ++r) {
        int row = m0 + wm + i * 16 + g * 4 + r;
        int col = n0 + wn + j * 16 + m16;
        store1(&C[(size_t)row * N + col], acc[i][j][r]);
      }
}

// ---------------------------------------------------------------------------
// RoPE + RMSNorm in place on fused qkv [M][3072]. One wave per (b,l,head).
// ---------------------------------------------------------------------------
__global__ __launch_bounds__(256) void rope_rms(unsigned short* __restrict__ qkv,
                                                const void* __restrict__ cosp,
                                                const void* __restrict__ sinp,
                                                const int* __restrict__ flags) {
  const bool cf = flags[1] != 0, sf = flags[2] != 0;
  const int wid = blockIdx.x * 4 + (threadIdx.x >> 6);
  const int lane = threadIdx.x & 63;
  const int hh = wid % (NH + NKV);
  const int bl = wid / (NH + NKV);
  const int l = bl & (LL - 1);
  unsigned short* base = (hh < NH) ? &qkv[(size_t)bl * QS + hh * 64]
                                   : &qkv[(size_t)bl * QS + KO + (hh - NH) * 64];
  const int j = lane & 31;
  float c = ld1_rt(cosp, l * 32 + j, cf);
  float s = ld1_rt(sinp, l * 32 + j, sf);
  float val = bfu2f(base[lane]);
  float other = __shfl_xor(val, 32);
  float r = (lane < 32) ? fmaf(val, c, -(other * s)) : fmaf(val, c, other * s);
  float ss = r * r;
#pragma unroll
  for (int off = 32; off; off >>= 1) ss += __shfl_xor(ss, off);
  base[lane] = f2bf(r * rsqrtf(ss * (1.0f / HD) + EPS));
}

// ---------------------------------------------------------------------------
// MFMA causal GQA flash attention with STATIC-MAX softmax.
// After RMSNorm |q|=|k|=8 => scores in [-8.07, 8.07]; use fixed m=8:
// p = exp(s*0.125 - 8). No running max, no alpha, no O-rescale; row-sum l is
// a plain sum accumulated per-lane, one butterfly at epilogue. Masked p = 0
// exactly (ref's exp(-10000-m) underflows to 0 too). O written in-place over
// the q columns (block-exclusive region).
// ---------------------------------------------------------------------------
__global__ __launch_bounds__(256) void attn_mfma(unsigned short* __restrict__ qkv) {
  __shared__ __align__(16) unsigned short Ks[64][72];     // [key][d]
  __shared__ __align__(16) unsigned short Vs[64][72];     // [d][key]
  __shared__ __align__(16) unsigned short Ps[4][16][72];  // per-wave P round-trip
  const int t = threadIdx.x, lane = t & 63, w = t >> 6;
  const int g = lane >> 4, m16 = lane & 15;
  const int h = blockIdx.x, b = blockIdx.y;
  const int qt = (LL / 64 - 1) - blockIdx.z;  // longest blocks dispatch first
  const int kvh = h >> 2;
  const int q0 = qt * 64, qr0 = q0 + w * 16;

  bf16x8 qf0, qf1;
  {
    const unsigned short* qrow = &qkv[(size_t)(b * LL + qr0 + m16) * QS + h * 64 + g * 8];
    qf0 = *(const bf16x8*)&qrow[0];
    qf1 = *(const bf16x8*)&qrow[32];
  }
  f32x4 Oacc[4] = {};
  float lrow[4] = {0.f, 0.f, 0.f, 0.f};

  for (int j0 = 0; j0 <= q0; j0 += 64) {
    __syncthreads();  // protect Ks/Vs from overwrite while still in use
    {
      const int kr = lane, seg = w * 16;
      const unsigned short* kvrow = &qkv[(size_t)(b * LL + j0 + kr) * QS + kvh * 64 + seg];
      *(uint4*)&Ks[kr][seg] = *(const uint4*)&kvrow[KO];
      *(uint4*)&Ks[kr][seg + 8] = *(const uint4*)&kvrow[KO + 8];
      unsigned short vv[16];
      *(uint4*)&vv[0] = *(const uint4*)&kvrow[VO];
      *(uint4*)&vv[8] = *(const uint4*)&kvrow[VO + 8];
#pragma unroll
      for (int jj = 0; jj < 16; ++jj) Vs[seg + jj][kr] = vv[jj];
    }
    __syncthreads();

    // S = Q K^T
    f32x4 S[4];
#pragma unroll
    for (int jt = 0; jt < 4; ++jt) {
      bf16x8 kf0 = *(const bf16x8*)&Ks[jt * 16 + m16][g * 8];
      bf16x8 kf1 = *(const bf16x8*)&Ks[jt * 16 + m16][32 + g * 8];
      f32x4 z = {0.f, 0.f, 0.f, 0.f};
      z = __builtin_amdgcn_mfma_f32_16x16x32_bf16(qf0, kf0, z, 0, 0, 0);
      S[jt] = __builtin_amdgcn_mfma_f32_16x16x32_bf16(qf1, kf1, z, 0, 0, 0);
    }
    // static-max softmax: p = exp(s/8 - 8); mask only on the diagonal tile
    if (j0 == q0) {
#pragma unroll
      for (int jt = 0; jt < 4; ++jt)
#pragma unroll
        for (int r = 0; r < 4; ++r) {
          int col = q0 + jt * 16 + m16;
          int row = qr0 + g * 4 + r;
          float p = __expf(fmaf(S[jt][r], 0.125f, -8.0f));
          p = (col <= row) ? p : 0.f;
          S[jt][r] = p;
          lrow[r] += p;
        }
    } else {
#pragma unroll
      for (int jt = 0; jt < 4; ++jt)
#pragma unroll
        for (int r = 0; r < 4; ++r) {
          float p = __expf(fmaf(S[jt][r], 0.125f, -8.0f));
          S[jt][r] = p;
          lrow[r] += p;
        }
    }
    // P -> LDS (C-layout), reload as A-layout frags
#pragma unroll
    for (int jt = 0; jt < 4; ++jt)
#pragma unroll
      for (int r = 0; r < 4; ++r)
        Ps[w][g * 4 + r][jt * 16 + m16] = f2bf(S[jt][r]);
    __syncthreads();
    bf16x8 pf0 = *(const bf16x8*)&Ps[w][m16][g * 8];
    bf16x8 pf1 = *(const bf16x8*)&Ps[w][m16][32 + g * 8];
    // O += P V
#pragma unroll
    for (int dt = 0; dt < 4; ++dt) {
      bf16x8 vf0 = *(const bf16x8*)&Vs[dt * 16 + m16][g * 8];
      bf16x8 vf1 = *(const bf16x8*)&Vs[dt * 16 + m16][32 + g * 8];
      Oacc[dt] = __builtin_amdgcn_mfma_f32_16x16x32_bf16(pf0, vf0, Oacc[dt], 0, 0, 0);
      Oacc[dt] = __builtin_amdgcn_mfma_f32_16x16x32_bf16(pf1, vf1, Oacc[dt], 0, 0, 0);
    }
  }
  // epilogue: reduce l across the 16-lane column groups, normalize, store
  float inv[4];
#pragma unroll
  for (int r = 0; r < 4; ++r) {
#pragma unroll
    for (int off = 1; off < 16; off <<= 1) lrow[r] += __shfl_xor(lrow[r], off);
    inv[r] = 1.0f / lrow[r];
  }
#pragma unroll
  for (int dt = 0; dt < 4; ++dt)
#pragma unroll
    for (int r = 0; r < 4; ++r) {
      int row = qr0 + g * 4 + r;
      qkv[(size_t)(b * LL + row) * QS + h * 64 + dt * 16 + m16] = f2bf(Oacc[dt][r] * inv[r]);
    }
}

// ---------------------------------------------------------------------------
extern "C" void kernel_launch(void* const* d_in, const int* in_sizes, int n_in,
                              void* d_out, int out_size, void* d_ws, size_t ws_size,
                              hipStream_t stream) {
  const void* x = d_in[0];
  const void* cosp = d_in[1];
  const void* sinp = d_in[2];
  const void* Wq = d_in[3];
  const void* Wk = d_in[4];
  const void* Wv = d_in[5];
  const void* Wo = d_in[6];
  float* out = (float*)d_out;

  // ws (bf16): xb [4096][2048] | qkvb [4096][3072] | WqkvT [3072][2048] | WoT [2048][2048]
  char* w0 = (char*)d_ws;
  int* flags = (int*)w0;
  unsigned short* xb = (unsigned short*)(w0 + 256);
  unsigned short* qkvb = xb + (size_t)MM * 2048;
  unsigned short* WqkvT = qkvb + (size_t)MM * QS;
  unsigned short* WoT = WqkvT + (size_t)QS * 2048;

  detect_all<<<7, 256, 0, stream>>>(
      (const unsigned short*)x, (const unsigned short*)cosp, (const unsigned short*)sinp,
      (const unsigned short*)Wq, (const unsigned short*)Wk, (const unsigned short*)Wv,
      (const unsigned short*)Wo, flags);
  cvt_bf16<<<MM * 2048 / 4 / 256, 256, 0, stream>>>(x, xb, MM * 2048 / 4, flags, 0);
  transpose_any<<<dim3(2048 / 64, 2048 / 64), 256, 0, stream>>>(Wq, WqkvT, 2048, 2048, flags, 3);
  transpose_any<<<dim3(512 / 64, 2048 / 64), 256, 0, stream>>>(Wk, WqkvT + (size_t)KO * 2048, 2048, 512, flags, 4);
  transpose_any<<<dim3(512 / 64, 2048 / 64), 256, 0, stream>>>(Wv, WqkvT + (size_t)VO * 2048, 2048, 512, flags, 5);
  transpose_any<<<dim3(2048 / 64, 2048 / 64), 256, 0, stream>>>(Wo, WoT, 2048, 2048, flags, 6);
  // fused QKV projection: [4096,2048] @ [2048,3072] -> qkvb
  gemm_mfma<unsigned short><<<dim3(QS / 128, MM / 128), 256, 0, stream>>>(xb, WqkvT, qkvb, MM, QS, 2048, 2048);
  rope_rms<<<MM * (NH + NKV) / 4, 256, 0, stream>>>(qkvb, cosp, sinp, flags);
  // causal GQA attention, O in-place into q columns; longest qt first (grid.z reversed)
  attn_mfma<<<dim3(NH, BB, LL / 64), 256, 0, stream>>>(qkvb);
  // output projection: qkv's q columns (lda=3072) @ WoT -> f32 out
  gemm_mfma<float><<<dim3(2048 / 128, MM / 128), 256, 0, stream>>>(qkvb, WoT, out, MM, 2048, 2048, QS);
}

// Round 8
// 374.822 us; speedup vs baseline: 11.1908x; 1.5739x over previous
//
#include <hip/hip_runtime.h>
#include <hip/hip_bf16.h>
#include <cstdint>
#include <cstddef>

#define D_MODEL 2048
#define NH 32
#define NKV 8
#define HD 64
#define BB 2
#define LL 2048
#define EPS 1e-6f
#define MM (BB * LL)   // 4096
#define QS 3072        // fused qkv row stride
#define KO 2048        // k column offset in qkv
#define VO 2560        // v column offset in qkv

typedef __hip_bfloat16 bf16;
typedef short bf16x8 __attribute__((ext_vector_type(8)));
typedef float f32x4 __attribute__((ext_vector_type(4)));

// ---- dtype helpers ---------------------------------------------------------
__device__ inline float4 ld_bf4u(const unsigned short* p) {
  const ushort4 u = *(const ushort4*)p;
  float4 r;
  r.x = __uint_as_float(((unsigned)u.x) << 16);
  r.y = __uint_as_float(((unsigned)u.y) << 16);
  r.z = __uint_as_float(((unsigned)u.z) << 16);
  r.w = __uint_as_float(((unsigned)u.w) << 16);
  return r;
}
__device__ inline float4 ld4_rt(const void* p, size_t i, bool f32) {
  if (f32) return *(const float4*)((const float*)p + i);
  return ld_bf4u((const unsigned short*)p + i);
}
__device__ inline float ld1_rt(const void* p, size_t i, bool f32) {
  if (f32) return ((const float*)p)[i];
  unsigned short u = ((const unsigned short*)p)[i];
  return __uint_as_float(((unsigned)u) << 16);
}
__device__ inline unsigned short f2bf(float f) {
  bf16 h = __float2bfloat16(f);  // RNE
  return *reinterpret_cast<unsigned short*>(&h);
}
__device__ inline float bfu2f(unsigned short u) {
  return __uint_as_float(((unsigned)u) << 16);
}
__device__ inline void store1(float* p, float v) { *p = v; }
__device__ inline void store1(unsigned short* p, float v) { *p = f2bf(v); }

// async global->LDS, 16 B per lane; LDS dest must be wave-uniform base + lane*16
__device__ inline void glds16(const unsigned short* g, unsigned short* l) {
  __builtin_amdgcn_global_load_lds(
      (const __attribute__((address_space(1))) unsigned int*)g,
      (__attribute__((address_space(3))) unsigned int*)l, 16, 0, 0);
}

// ---- per-input dtype detector (sampled, vectorized) ------------------------
// A u16 word with bits[14:7]==0xFF is impossible in finite bf16 data but
// occurs with p~=0.4% per word in f32 lo-mantissa halves. Sampling 32768
// words: P(miss f32) = 0.996^32768 ~ e^-131. One block per input, 16 iters
// of coalesced uint4 (64 KB) -> ~3 us instead of R7's 234 us serial scan.
__global__ __launch_bounds__(256) void detect_all(
    const unsigned short* p0, const unsigned short* p1, const unsigned short* p2,
    const unsigned short* p3, const unsigned short* p4, const unsigned short* p5,
    const unsigned short* p6, int* __restrict__ flags) {
  const unsigned short* ptrs[7] = {p0, p1, p2, p3, p4, p5, p6};
  const int b = blockIdx.x;
  const uint4* p = (const uint4*)ptrs[b];  // 8 words per uint4
  __shared__ int found;
  if (threadIdx.x == 0) found = 0;
  __syncthreads();
  int loc = 0;
#pragma unroll
  for (int it = 0; it < 16; ++it) {
    uint4 v = p[it * 256 + threadIdx.x];
    unsigned wds[4] = {v.x, v.y, v.z, v.w};
#pragma unroll
    for (int q = 0; q < 4; ++q) {
      unsigned lo = wds[q] & 0xFFFFu, hi = wds[q] >> 16;
      if (((lo >> 7) & 0xFFu) == 0xFFu || ((hi >> 7) & 0xFFu) == 0xFFu) loc = 1;
    }
  }
  if (loc) atomicOr(&found, 1);
  __syncthreads();
  if (threadIdx.x == 0) flags[b] = found;
}

// ---- prep: elementwise convert to bf16 -------------------------------------
__global__ __launch_bounds__(256) void cvt_bf16(const void* __restrict__ src,
                                                unsigned short* __restrict__ dst,
                                                int n4, const int* __restrict__ flags, int idx) {
  const bool f32 = flags[idx] != 0;
  int i = blockIdx.x * 256 + threadIdx.x;
  if (i < n4) {
    float4 v = ld4_rt(src, (size_t)i * 4, f32);
    ushort4 o;
    o.x = f2bf(v.x); o.y = f2bf(v.y); o.z = f2bf(v.z); o.w = f2bf(v.w);
    *(ushort4*)&dst[(size_t)i * 4] = o;
  }
}

// ---- prep: transpose [K][N] -> [N][K] bf16 ---------------------------------
__global__ __launch_bounds__(256) void transpose_any(const void* __restrict__ src,
                                                     unsigned short* __restrict__ dst,
                                                     int K, int N,
                                                     const int* __restrict__ flags, int idx) {
  const bool f32 = flags[idx] != 0;
  __shared__ unsigned short tile[64][65];
  const int t = threadIdx.x;
  const int n0 = blockIdx.x * 64, k0 = blockIdx.y * 64;
  const int cr = t >> 4, cc = (t & 15) * 4;
#pragma unroll
  for (int rr = 0; rr < 4; ++rr) {
    int row = rr * 16 + cr;
    float4 v = ld4_rt(src, (size_t)(k0 + row) * N + n0 + cc, f32);
    tile[row][cc + 0] = f2bf(v.x);
    tile[row][cc + 1] = f2bf(v.y);
    tile[row][cc + 2] = f2bf(v.z);
    tile[row][cc + 3] = f2bf(v.w);
  }
  __syncthreads();
#pragma unroll
  for (int rr = 0; rr < 4; ++rr) {
    int nrow = rr * 16 + cr;
    ushort4 o;
    o.x = tile[cc + 0][nrow];
    o.y = tile[cc + 1][nrow];
    o.z = tile[cc + 2][nrow];
    o.w = tile[cc + 3][nrow];
    *(ushort4*)&dst[(size_t)(n0 + nrow) * K + k0 + cc] = o;
  }
}

// ---------------------------------------------------------------------------
// MFMA GEMM (m97 structure): C[M,N] = A[M,K]@Bt[N,K]^T, bf16 in, CT out.
// 128x128 tile, BK=32, global_load_lds width-16 staging, 2-barrier K-loop.
// ---------------------------------------------------------------------------
template <typename CT>
__global__ __launch_bounds__(256) void gemm_mfma(const unsigned short* __restrict__ A,
                                                 const unsigned short* __restrict__ Bt,
                                                 CT* __restrict__ C,
                                                 int M, int N, int K, int lda) {
  __shared__ __align__(16) unsigned short As[128 * 32];  // row-major [128][32]
  __shared__ __align__(16) unsigned short Bs[128 * 32];
  const int t = threadIdx.x;
  const int lane = t & 63, w = t >> 6;
  const int wm = (w >> 1) * 64, wn = (w & 1) * 64;
  const int g = lane >> 4, m16 = lane & 15;
  const int m0 = blockIdx.y * 128, n0 = blockIdx.x * 128;
  const unsigned short* gA = &A[(size_t)(m0 + (t >> 2)) * lda + (t & 3) * 8];
  const unsigned short* gB = &Bt[(size_t)(n0 + (t >> 2)) * K + (t & 3) * 8];
  unsigned short* lA = &As[t * 8];
  unsigned short* lB = &Bs[t * 8];
  f32x4 acc[4][4] = {};
  for (int k0 = 0; k0 < K; k0 += 32) {
    __syncthreads();  // prev iteration's frag reads done
    glds16(gA + k0, lA);
    glds16(gA + (size_t)64 * lda + k0, lA + 2048);
    glds16(gB + k0, lB);
    glds16(gB + (size_t)64 * K + k0, lB + 2048);
    __syncthreads();  // drains vmcnt -> staged data visible
    bf16x8 af[4], bfr[4];
#pragma unroll
    for (int i = 0; i < 4; ++i) af[i] = *(const bf16x8*)&As[(wm + i * 16 + m16) * 32 + g * 8];
#pragma unroll
    for (int j = 0; j < 4; ++j) bfr[j] = *(const bf16x8*)&Bs[(wn + j * 16 + m16) * 32 + g * 8];
#pragma unroll
    for (int i = 0; i < 4; ++i)
#pragma unroll
      for (int j = 0; j < 4; ++j)
        acc[i][j] = __builtin_amdgcn_mfma_f32_16x16x32_bf16(af[i], bfr[j], acc[i][j], 0, 0, 0);
  }
#pragma unroll
  for (int i = 0; i < 4; ++i)
#pragma unroll
    for (int j = 0; j < 4; ++j)
#pragma unroll
      for (int r = 0; r < 4; ++r) {
        int row = m0 + wm + i * 16 + g * 4 + r;
        int col = n0 + wn + j * 16 + m16;
        store1(&C[(size_t)row * N + col], acc[i][j][r]);
      }
}

// ---------------------------------------------------------------------------
// RoPE + RMSNorm in place on fused qkv [M][3072]. One wave per (b,l,head).
// ---------------------------------------------------------------------------
__global__ __launch_bounds__(256) void rope_rms(unsigned short* __restrict__ qkv,
                                                const void* __restrict__ cosp,
                                                const void* __restrict__ sinp,
                                                const int* __restrict__ flags) {
  const bool cf = flags[1] != 0, sf = flags[2] != 0;
  const int wid = blockIdx.x * 4 + (threadIdx.x >> 6);
  const int lane = threadIdx.x & 63;
  const int hh = wid % (NH + NKV);
  const int bl = wid / (NH + NKV);
  const int l = bl & (LL - 1);
  unsigned short* base = (hh < NH) ? &qkv[(size_t)bl * QS + hh * 64]
                                   : &qkv[(size_t)bl * QS + KO + (hh - NH) * 64];
  const int j = lane & 31;
  float c = ld1_rt(cosp, l * 32 + j, cf);
  float s = ld1_rt(sinp, l * 32 + j, sf);
  float val = bfu2f(base[lane]);
  float other = __shfl_xor(val, 32);
  float r = (lane < 32) ? fmaf(val, c, -(other * s)) : fmaf(val, c, other * s);
  float ss = r * r;
#pragma unroll
  for (int off = 32; off; off >>= 1) ss += __shfl_xor(ss, off);
  base[lane] = f2bf(r * rsqrtf(ss * (1.0f / HD) + EPS));
}

// ---------------------------------------------------------------------------
// MFMA causal GQA flash attention with STATIC-MAX softmax.
// After RMSNorm |q|=|k|=8 => scores in [-8.07, 8.07]; fixed m=8:
// p = exp(s*0.125 - 8). No running max/alpha/rescale; l accumulated per-lane,
// one butterfly at epilogue. O written in-place over the q columns.
// ---------------------------------------------------------------------------
__global__ __launch_bounds__(256) void attn_mfma(unsigned short* __restrict__ qkv) {
  __shared__ __align__(16) unsigned short Ks[64][72];     // [key][d]
  __shared__ __align__(16) unsigned short Vs[64][72];     // [d][key]
  __shared__ __align__(16) unsigned short Ps[4][16][72];  // per-wave P round-trip
  const int t = threadIdx.x, lane = t & 63, w = t >> 6;
  const int g = lane >> 4, m16 = lane & 15;
  const int h = blockIdx.x, b = blockIdx.y;
  const int qt = (LL / 64 - 1) - blockIdx.z;  // longest blocks dispatch first
  const int kvh = h >> 2;
  const int q0 = qt * 64, qr0 = q0 + w * 16;

  bf16x8 qf0, qf1;
  {
    const unsigned short* qrow = &qkv[(size_t)(b * LL + qr0 + m16) * QS + h * 64 + g * 8];
    qf0 = *(const bf16x8*)&qrow[0];
    qf1 = *(const bf16x8*)&qrow[32];
  }
  f32x4 Oacc[4] = {};
  float lrow[4] = {0.f, 0.f, 0.f, 0.f};

  for (int j0 = 0; j0 <= q0; j0 += 64) {
    __syncthreads();  // protect Ks/Vs from overwrite while still in use
    {
      const int kr = lane, seg = w * 16;
      const unsigned short* kvrow = &qkv[(size_t)(b * LL + j0 + kr) * QS + kvh * 64 + seg];
      *(uint4*)&Ks[kr][seg] = *(const uint4*)&kvrow[KO];
      *(uint4*)&Ks[kr][seg + 8] = *(const uint4*)&kvrow[KO + 8];
      unsigned short vv[16];
      *(uint4*)&vv[0] = *(const uint4*)&kvrow[VO];
      *(uint4*)&vv[8] = *(const uint4*)&kvrow[VO + 8];
#pragma unroll
      for (int jj = 0; jj < 16; ++jj) Vs[seg + jj][kr] = vv[jj];
    }
    __syncthreads();

    // S = Q K^T
    f32x4 S[4];
#pragma unroll
    for (int jt = 0; jt < 4; ++jt) {
      bf16x8 kf0 = *(const bf16x8*)&Ks[jt * 16 + m16][g * 8];
      bf16x8 kf1 = *(const bf16x8*)&Ks[jt * 16 + m16][32 + g * 8];
      f32x4 z = {0.f, 0.f, 0.f, 0.f};
      z = __builtin_amdgcn_mfma_f32_16x16x32_bf16(qf0, kf0, z, 0, 0, 0);
      S[jt] = __builtin_amdgcn_mfma_f32_16x16x32_bf16(qf1, kf1, z, 0, 0, 0);
    }
    // static-max softmax: p = exp(s/8 - 8); mask only on the diagonal tile
    if (j0 == q0) {
#pragma unroll
      for (int jt = 0; jt < 4; ++jt)
#pragma unroll
        for (int r = 0; r < 4; ++r) {
          int col = q0 + jt * 16 + m16;
          int row = qr0 + g * 4 + r;
          float p = __expf(fmaf(S[jt][r], 0.125f, -8.0f));
          p = (col <= row) ? p : 0.f;
          S[jt][r] = p;
          lrow[r] += p;
        }
    } else {
#pragma unroll
      for (int jt = 0; jt < 4; ++jt)
#pragma unroll
        for (int r = 0; r < 4; ++r) {
          float p = __expf(fmaf(S[jt][r], 0.125f, -8.0f));
          S[jt][r] = p;
          lrow[r] += p;
        }
    }
    // P -> LDS (C-layout), reload as A-layout frags
#pragma unroll
    for (int jt = 0; jt < 4; ++jt)
#pragma unroll
      for (int r = 0; r < 4; ++r)
        Ps[w][g * 4 + r][jt * 16 + m16] = f2bf(S[jt][r]);
    __syncthreads();
    bf16x8 pf0 = *(const bf16x8*)&Ps[w][m16][g * 8];
    bf16x8 pf1 = *(const bf16x8*)&Ps[w][m16][32 + g * 8];
    // O += P V
#pragma unroll
    for (int dt = 0; dt < 4; ++dt) {
      bf16x8 vf0 = *(const bf16x8*)&Vs[dt * 16 + m16][g * 8];
      bf16x8 vf1 = *(const bf16x8*)&Vs[dt * 16 + m16][32 + g * 8];
      Oacc[dt] = __builtin_amdgcn_mfma_f32_16x16x32_bf16(pf0, vf0, Oacc[dt], 0, 0, 0);
      Oacc[dt] = __builtin_amdgcn_mfma_f32_16x16x32_bf16(pf1, vf1, Oacc[dt], 0, 0, 0);
    }
  }
  // epilogue: reduce l across the 16-lane column groups, normalize, store
  float inv[4];
#pragma unroll
  for (int r = 0; r < 4; ++r) {
#pragma unroll
    for (int off = 1; off < 16; off <<= 1) lrow[r] += __shfl_xor(lrow[r], off);
    inv[r] = 1.0f / lrow[r];
  }
#pragma unroll
  for (int dt = 0; dt < 4; ++dt)
#pragma unroll
    for (int r = 0; r < 4; ++r) {
      int row = qr0 + g * 4 + r;
      qkv[(size_t)(b * LL + row) * QS + h * 64 + dt * 16 + m16] = f2bf(Oacc[dt][r] * inv[r]);
    }
}

// ---------------------------------------------------------------------------
extern "C" void kernel_launch(void* const* d_in, const int* in_sizes, int n_in,
                              void* d_out, int out_size, void* d_ws, size_t ws_size,
                              hipStream_t stream) {
  const void* x = d_in[0];
  const void* cosp = d_in[1];
  const void* sinp = d_in[2];
  const void* Wq = d_in[3];
  const void* Wk = d_in[4];
  const void* Wv = d_in[5];
  const void* Wo = d_in[6];
  float* out = (float*)d_out;

  // ws (bf16): xb [4096][2048] | qkvb [4096][3072] | WqkvT [3072][2048] | WoT [2048][2048]
  char* w0 = (char*)d_ws;
  int* flags = (int*)w0;
  unsigned short* xb = (unsigned short*)(w0 + 256);
  unsigned short* qkvb = xb + (size_t)MM * 2048;
  unsigned short* WqkvT = qkvb + (size_t)MM * QS;
  unsigned short* WoT = WqkvT + (size_t)QS * 2048;

  detect_all<<<7, 256, 0, stream>>>(
      (const unsigned short*)x, (const unsigned short*)cosp, (const unsigned short*)sinp,
      (const unsigned short*)Wq, (const unsigned short*)Wk, (const unsigned short*)Wv,
      (const unsigned short*)Wo, flags);
  cvt_bf16<<<MM * 2048 / 4 / 256, 256, 0, stream>>>(x, xb, MM * 2048 / 4, flags, 0);
  transpose_any<<<dim3(2048 / 64, 2048 / 64), 256, 0, stream>>>(Wq, WqkvT, 2048, 2048, flags, 3);
  transpose_any<<<dim3(512 / 64, 2048 / 64), 256, 0, stream>>>(Wk, WqkvT + (size_t)KO * 2048, 2048, 512, flags, 4);
  transpose_any<<<dim3(512 / 64, 2048 / 64), 256, 0, stream>>>(Wv, WqkvT + (size_t)VO * 2048, 2048, 512, flags, 5);
  transpose_any<<<dim3(2048 / 64, 2048 / 64), 256, 0, stream>>>(Wo, WoT, 2048, 2048, flags, 6);
  // fused QKV projection: [4096,2048] @ [2048,3072] -> qkvb
  gemm_mfma<unsigned short><<<dim3(QS / 128, MM / 128), 256, 0, stream>>>(xb, WqkvT, qkvb, MM, QS, 2048, 2048);
  rope_rms<<<MM * (NH + NKV) / 4, 256, 0, stream>>>(qkvb, cosp, sinp, flags);
  // causal GQA attention, O in-place into q columns; longest qt first (grid.z reversed)
  attn_mfma<<<dim3(NH, BB, LL / 64), 256, 0, stream>>>(qkvb);
  // output projection: qkv's q columns (lda=3072) @ WoT -> f32 out
  gemm_mfma<float><<<dim3(2048 / 128, MM / 128), 256, 0, stream>>>(qkvb, WoT, out, MM, 2048, 2048, QS);
}